// Round 8
// baseline (153.440 us; speedup 1.0000x reference)
//
#include <hip/hip_runtime.h>

typedef unsigned short u16;
typedef unsigned int u32;
typedef __bf16 bf16x8 __attribute__((ext_vector_type(8)));
typedef float f32x16 __attribute__((ext_vector_type(16)));

#define C2 (-7.213475204444817f) /* -5/ln2 : exp(-5 t^2) = exp2(C2 t^2) */
#define T1C 0.28650480f          /* e^-1.25 */
#define T2C 0.0067379470f        /* e^-5    */

__device__ __forceinline__ u16 f2bf(float f) {
  u32 u = __float_as_uint(f);
  return (u16)((u + 0x7FFFu + ((u >> 16) & 1u)) >> 16);  // RNE
}

__device__ __forceinline__ f32x16 mfma16(uint4 a, uint4 b, f32x16 c) {
  return __builtin_amdgcn_mfma_f32_32x32x16_bf16(
      __builtin_bit_cast(bf16x8, a), __builtin_bit_cast(bf16x8, b), c, 0, 0, 0);
}

// ---------------------------------------------------------------------------
// Prep (unchanged; validated): f32 weights -> bf16, per-16k-chunk fragment
// order. wst3 granule(c, g) 16 B, g = s*256 + nq*64 + l:
//   content = W_s[k = c*16 + (l>>5)*8 + 0..8)[u = nq*32 + (l&31)]
// ---------------------------------------------------------------------------
__global__ __launch_bounds__(256) void kan_prep(const float* __restrict__ wb,
                                                const float* __restrict__ ws,
                                                u16* __restrict__ wst3) {
  __shared__ u16 tile[6][16][130];
  const int t = threadIdx.x;
  const int c = blockIdx.x;
#pragma unroll
  for (int it = 0; it < 8; ++it) {
    int idx = it * 256 + t;
    int d = idx >> 7, u = idx & 127;
    size_t base = (size_t)(c * 16 + d) * 128 + u;
    const float* p = ws + base * 8;
    float4 v0 = *(const float4*)p;
    float g4 = p[4];
    tile[0][d][u] = f2bf(v0.x);
    tile[1][d][u] = f2bf(v0.y);
    tile[2][d][u] = f2bf(v0.z);
    tile[3][d][u] = f2bf(v0.w);
    tile[4][d][u] = f2bf(g4);
    tile[5][d][u] = f2bf(wb[base]);
  }
  __syncthreads();
#pragma unroll
  for (int i = 0; i < 6; ++i) {
    int g = i * 256 + t;
    int s = g >> 8, r = g & 255;
    int nq = r >> 6, l = r & 63;
    int u = nq * 32 + (l & 31);
    int dbase = (l >> 5) * 8;
    u32 q[4];
#pragma unroll
    for (int j = 0; j < 4; ++j) {
      u32 lo = tile[s][dbase + 2 * j][u];
      u32 hi = tile[s][dbase + 2 * j + 1][u];
      q[j] = lo | (hi << 16);
    }
    uint4 w4; w4.x = q[0]; w4.y = q[1]; w4.z = q[2]; w4.w = q[3];
    *(uint4*)(wst3 + (size_t)c * 12288 + (size_t)g * 8) = w4;
  }
}

// ---------------------------------------------------------------------------
// Main R15: ZERO-BARRIER self-paced waves.  256 blocks x 512 thr = 8 waves
// (kc = k-half, wn = n-half, wm = m-half); wave tile 32m x 64n x 512k; acc
// sp0,sp1,ba0,ba1 (64 AGPR).  NO LDS and NO __syncthreads in the K-loop:
// each lane computes its OWN A-fragments in registers (R10's validated
// mkfrag: lane l needs x[m=l&31][c*16+(l>>5)*8 ..+8], exactly its MFMA
// A-frag), and B streams from L2 (fragment-ordered wst3) through a 6+6
// uint4 register ring refilled immediately after last use (~540 cyc cover
// vs ~300 cyc L2 latency).  x is read one 4-chunk window (32 floats/lane)
// ahead; a wave's two kh-halves cover complementary 32B of each row ->
// 100% cache-line efficiency.  Waves drift freely; the 2 waves/SIMD fill
// each other's stalls (TLP) instead of phase-locking at barriers.
// One barrier total: before the kc-merge epilogue (kc=1 -> LDS 64 KB,
// kc=0 merges + silu + store).  mfma A[m=lane&31][k=(lane>>5)*8+j];
// C/D col=lane&31, row=(reg&3)+8*(reg>>2)+4*(lane>>5)  (validated R2-R14).
// ---------------------------------------------------------------------------
__global__ __launch_bounds__(512, 2) void kan_main(const float* __restrict__ x,
                                                   const u16* __restrict__ wst3,
                                                   float* __restrict__ out) {
  __shared__ __align__(16) char lds[65536];  // epilogue only

  const int t = threadIdx.x;
  const int lane = t & 63;
  const int w = t >> 6;
  const int kc = w >> 2;         // k-half: chunks kc*32 .. +31
  const int wn = (w >> 1) & 1;   // n-half: cols wn*64 .. +63
  const int wm = w & 1;          // m-half: rows wm*32 .. +31
  const int b0 = blockIdx.x * 64;
  const int m = lane & 31, kh = lane >> 5;

  const float* xp = x + (size_t)(b0 + wm * 32 + m) * 1024 + kc * 512 + kh * 8;
  const char* bp = (const char*)wst3 + (size_t)kc * 32 * 24576 + wn * 2048 +
                   (size_t)lane * 16;

  f32x16 sp0, sp1, ba0, ba1;
#pragma unroll
  for (int i = 0; i < 16; ++i) { sp0[i] = 0.f; sp1[i] = 0.f; ba0[i] = 0.f; ba1[i] = 0.f; }

  uint4 bA[6], bB[6];  // slabs 0-2 / 3-5 of current chunk, x2 n-quads
  float4 xw[8];        // current 4-chunk x window (32 floats)

  auto ldb = [&](int chunk, int s, int q) {
    return *(const uint4*)(bp + (size_t)chunk * 24576 + s * 4096 + q * 1024);
  };

  // 8 x floats -> 6 A-frags (verbatim R10 mkfrag; validated)
  auto mkfrag = [&](const float4& xa, const float4& xb, uint4* fr) {
    float xf[8] = {xa.x, xa.y, xa.z, xa.w, xb.x, xb.y, xb.z, xb.w};
    u32 pk[6][4];
#pragma unroll
    for (int pp = 0; pp < 4; ++pp) {
      u32 lo6[6], hi6[6];
#pragma unroll
      for (int e = 0; e < 2; ++e) {
        float xv = xf[2 * pp + e];
        float t0 = C2 * xv;
        float P = __builtin_amdgcn_exp2f(t0 * xv);  // e^{-5x^2}
        float Qp = __builtin_amdgcn_exp2f(-t0);     // e^{+5x}
        float Qm = __builtin_amdgcn_exp2f(t0);      // e^{-5x}
        float PQ = P * Qp, PQm = P * Qm;
        u32* dst = e ? hi6 : lo6;
        dst[0] = __float_as_uint(PQm * Qm * T2C) + 0x8000u;
        dst[1] = __float_as_uint(PQm * T1C) + 0x8000u;
        dst[2] = __float_as_uint(P) + 0x8000u;
        dst[3] = __float_as_uint(PQ * T1C) + 0x8000u;
        dst[4] = __float_as_uint(PQ * Qp * T2C) + 0x8000u;
        dst[5] = __float_as_uint(xv) + 0x8000u;
      }
#pragma unroll
      for (int s = 0; s < 6; ++s)
        pk[s][pp] = __builtin_amdgcn_perm(hi6[s], lo6[s], 0x07060302);
    }
#pragma unroll
    for (int s = 0; s < 6; ++s) {
      fr[s].x = pk[s][0]; fr[s].y = pk[s][1];
      fr[s].z = pk[s][2]; fr[s].w = pk[s][3];
    }
  };

  // per-chunk body: mkfrag -> MFMA(slabs0-2) -> refill bA -> MFMA(3-5) ->
  // refill bB.  Refills target chunk j+1; x refilled at window boundary.
  auto body = [&](int j, bool refillB, bool refillX, int w2, int ci) {
    uint4 fa[6];
    mkfrag(xw[2 * ci], xw[2 * ci + 1], fa);
    if (refillX) {
#pragma unroll
      for (int c2 = 0; c2 < 4; ++c2) {
        xw[2 * c2] = *(const float4*)(xp + (w2 + 1) * 64 + c2 * 16);
        xw[2 * c2 + 1] = *(const float4*)(xp + (w2 + 1) * 64 + c2 * 16 + 4);
      }
    }
#pragma unroll
    for (int s = 0; s < 3; ++s) {
      sp0 = mfma16(fa[s], bA[2 * s], sp0);
      sp1 = mfma16(fa[s], bA[2 * s + 1], sp1);
    }
    if (refillB) {
#pragma unroll
      for (int s = 0; s < 3; ++s) {
        bA[2 * s] = ldb(j + 1, s, 0);
        bA[2 * s + 1] = ldb(j + 1, s, 1);
      }
    }
    sp0 = mfma16(fa[3], bB[0], sp0);
    sp1 = mfma16(fa[3], bB[1], sp1);
    sp0 = mfma16(fa[4], bB[2], sp0);
    sp1 = mfma16(fa[4], bB[3], sp1);
    ba0 = mfma16(fa[5], bB[4], ba0);
    ba1 = mfma16(fa[5], bB[5], ba1);
    if (refillB) {
#pragma unroll
      for (int s = 0; s < 3; ++s) {
        bB[2 * s] = ldb(j + 1, s + 3, 0);
        bB[2 * s + 1] = ldb(j + 1, s + 3, 1);
      }
    }
  };

  // ---- prologue: x window 0 + B chunk 0
#pragma unroll
  for (int ci = 0; ci < 4; ++ci) {
    xw[2 * ci] = *(const float4*)(xp + ci * 16);
    xw[2 * ci + 1] = *(const float4*)(xp + ci * 16 + 4);
  }
#pragma unroll
  for (int s = 0; s < 3; ++s) {
    bA[2 * s] = ldb(0, s, 0);
    bA[2 * s + 1] = ldb(0, s, 1);
    bB[2 * s] = ldb(0, s + 3, 0);
    bB[2 * s + 1] = ldb(0, s + 3, 1);
  }

  // ---- main loop: 8 windows x 4 chunks, zero barriers
  for (int w2 = 0; w2 < 7; ++w2) {
#pragma unroll
    for (int ci = 0; ci < 4; ++ci) body(w2 * 4 + ci, true, ci == 3, w2, ci);
  }
#pragma unroll
  for (int ci = 0; ci < 4; ++ci) body(28 + ci, ci < 3, false, 7, ci);

  // ---- epilogue: kc=1 -> LDS; single barrier; kc=0 merges + silu + store
  char* slab = lds + (wm * 2 + wn) * 16384;
  if (kc == 1) {
#pragma unroll
    for (int rq = 0; rq < 4; ++rq) {
      *(float4*)(slab + 0 * 4096 + rq * 1024 + lane * 16) =
          make_float4(sp0[4 * rq], sp0[4 * rq + 1], sp0[4 * rq + 2], sp0[4 * rq + 3]);
      *(float4*)(slab + 1 * 4096 + rq * 1024 + lane * 16) =
          make_float4(sp1[4 * rq], sp1[4 * rq + 1], sp1[4 * rq + 2], sp1[4 * rq + 3]);
      *(float4*)(slab + 2 * 4096 + rq * 1024 + lane * 16) =
          make_float4(ba0[4 * rq], ba0[4 * rq + 1], ba0[4 * rq + 2], ba0[4 * rq + 3]);
      *(float4*)(slab + 3 * 4096 + rq * 1024 + lane * 16) =
          make_float4(ba1[4 * rq], ba1[4 * rq + 1], ba1[4 * rq + 2], ba1[4 * rq + 3]);
    }
  }
  __syncthreads();
  if (kc == 0) {
#pragma unroll
    for (int rq = 0; rq < 4; ++rq) {
      float4 v0 = *(const float4*)(slab + 0 * 4096 + rq * 1024 + lane * 16);
      float4 v1 = *(const float4*)(slab + 1 * 4096 + rq * 1024 + lane * 16);
      float4 v2 = *(const float4*)(slab + 2 * 4096 + rq * 1024 + lane * 16);
      float4 v3 = *(const float4*)(slab + 3 * 4096 + rq * 1024 + lane * 16);
      sp0[4 * rq] += v0.x; sp0[4 * rq + 1] += v0.y; sp0[4 * rq + 2] += v0.z; sp0[4 * rq + 3] += v0.w;
      sp1[4 * rq] += v1.x; sp1[4 * rq + 1] += v1.y; sp1[4 * rq + 2] += v1.z; sp1[4 * rq + 3] += v1.w;
      ba0[4 * rq] += v2.x; ba0[4 * rq + 1] += v2.y; ba0[4 * rq + 2] += v2.z; ba0[4 * rq + 3] += v2.w;
      ba1[4 * rq] += v3.x; ba1[4 * rq + 1] += v3.y; ba1[4 * rq + 2] += v3.z; ba1[4 * rq + 3] += v3.w;
    }
#pragma unroll
    for (int reg = 0; reg < 16; ++reg) {
      int row = wm * 32 + (reg & 3) + 8 * (reg >> 2) + 4 * (lane >> 5);
      float z0 = ba0[reg];
      float z1 = ba1[reg];
      float s0 = z0 / (1.0f + __expf(-z0));
      float s1 = z1 / (1.0f + __expf(-z1));
      out[(size_t)(b0 + row) * 128 + wn * 64 + 0 * 32 + (lane & 31)] = s0 + sp0[reg];
      out[(size_t)(b0 + row) * 128 + wn * 64 + 1 * 32 + (lane & 31)] = s1 + sp1[reg];
    }
  }
}

extern "C" void kernel_launch(void* const* d_in, const int* in_sizes, int n_in,
                              void* d_out, int out_size, void* d_ws, size_t ws_size,
                              hipStream_t stream) {
  const float* x  = (const float*)d_in[0];   // [16384][1024] f32
  const float* wb = (const float*)d_in[1];   // [1024][128]   f32
  const float* ws = (const float*)d_in[2];   // [1024][128][8] f32
  u16* wst3 = (u16*)d_ws;                    // [64][1536] granules, 1.5 MB
  float* out = (float*)d_out;                // [16384][128]  f32

  kan_prep<<<dim3(64), 256, 0, stream>>>(wb, ws, wst3);
  kan_main<<<dim3(256), 512, 0, stream>>>(x, wst3, out);
}

// Round 9
// 123.875 us; speedup vs baseline: 1.2387x; 1.2387x over previous
//
#include <hip/hip_runtime.h>

typedef unsigned short u16;
typedef unsigned int u32;
typedef __bf16 bf16x8 __attribute__((ext_vector_type(8)));
typedef float f32x16 __attribute__((ext_vector_type(16)));

#define C2 (-7.213475204444817f) /* -5/ln2 : exp(-5 t^2) = exp2(C2 t^2) */
#define T1C 0.28650480f          /* e^-1.25 */
#define T2C 0.0067379470f        /* e^-5    */

__device__ __forceinline__ u16 f2bf(float f) {
  u32 u = __float_as_uint(f);
  return (u16)((u + 0x7FFFu + ((u >> 16) & 1u)) >> 16);  // RNE
}

__device__ __forceinline__ f32x16 mfma16(uint4 a, uint4 b, f32x16 c) {
  return __builtin_amdgcn_mfma_f32_32x32x16_bf16(
      __builtin_bit_cast(bf16x8, a), __builtin_bit_cast(bf16x8, b), c, 0, 0, 0);
}

// ---------------------------------------------------------------------------
// Prep (unchanged; validated): f32 weights -> bf16, per-16k-chunk fragment
// order. wst3 granule(c, g) 16 B, g = s*256 + nq*64 + l:
//   content = W_s[k = c*16 + (l>>5)*8 + 0..8)[u = nq*32 + (l&31)]
// ---------------------------------------------------------------------------
__global__ __launch_bounds__(256) void kan_prep(const float* __restrict__ wb,
                                                const float* __restrict__ ws,
                                                u16* __restrict__ wst3) {
  __shared__ u16 tile[6][16][130];
  const int t = threadIdx.x;
  const int c = blockIdx.x;
#pragma unroll
  for (int it = 0; it < 8; ++it) {
    int idx = it * 256 + t;
    int d = idx >> 7, u = idx & 127;
    size_t base = (size_t)(c * 16 + d) * 128 + u;
    const float* p = ws + base * 8;
    float4 v0 = *(const float4*)p;
    float g4 = p[4];
    tile[0][d][u] = f2bf(v0.x);
    tile[1][d][u] = f2bf(v0.y);
    tile[2][d][u] = f2bf(v0.z);
    tile[3][d][u] = f2bf(v0.w);
    tile[4][d][u] = f2bf(g4);
    tile[5][d][u] = f2bf(wb[base]);
  }
  __syncthreads();
#pragma unroll
  for (int i = 0; i < 6; ++i) {
    int g = i * 256 + t;
    int s = g >> 8, r = g & 255;
    int nq = r >> 6, l = r & 63;
    int u = nq * 32 + (l & 31);
    int dbase = (l >> 5) * 8;
    u32 q[4];
#pragma unroll
    for (int j = 0; j < 4; ++j) {
      u32 lo = tile[s][dbase + 2 * j][u];
      u32 hi = tile[s][dbase + 2 * j + 1][u];
      q[j] = lo | (hi << 16);
    }
    uint4 w4; w4.x = q[0]; w4.y = q[1]; w4.z = q[2]; w4.w = q[3];
    *(uint4*)(wst3 + (size_t)c * 12288 + (size_t)g * 8) = w4;
  }
}

// ---------------------------------------------------------------------------
// Main R16 = R11 (best validated, 46.5 us) + T3/T4 counted-wait discipline:
//  * all 17 loop barriers are RAW s_barrier (no vmcnt/lgkm drain).  Producer
//    adds s_waitcnt lgkmcnt(0) before its barrier (slab visibility); its x
//    prefetch vmem stays in flight ACROSS barriers.  sched_barrier(0) after
//    each barrier pins the schedule (no ds_read hoist above rendezvous;
//    dbuf makes producer-side motion safe regardless).
//  * consumer B-loads: per p-phase issue NEXT chunk's 6 dwordx4 into the
//    alternate register set (bvE/bvO ping-pong, static by p&1), consume the
//    current set -> every phase is {6 vmem issue || 12 ds_read || 12 MFMA},
//    ~500 cyc of cover per B sextet, and vmcnt is never drained to 0.
// Geometry/layouts verbatim R11 (validated): waves 0..3 producers (rbf ->
// LDS dbuf 2x48KB, computed once), waves 4..11... no: 512 thr, waves 4..7
// consumers, wn = n-quad, full K per wave, acc[0,1]=spline g0/g1,
// acc[2,3]=base.  A granule (s,g,p,kh): byte s*8192 + (g*4+p)*1024 + kh*512
// + ((m^(p*2+kh))&31)*16; B: chunk c: c*24576 + s*4096 + wn*1024 + lane*16;
// mfma A[m=lane&31][k=(lane>>5)*8+j]; C/D col=lane&31,
// row=(reg&3)+8*(reg>>2)+4*(lane>>5).  Epilogue verbatim R11.
// ---------------------------------------------------------------------------
#define RBAR()                            \
  do {                                    \
    __builtin_amdgcn_s_barrier();         \
    __builtin_amdgcn_sched_barrier(0);    \
  } while (0)
#define PBAR()                                          \
  do {                                                  \
    asm volatile("s_waitcnt lgkmcnt(0)" ::: "memory");  \
    __builtin_amdgcn_s_barrier();                       \
    __builtin_amdgcn_sched_barrier(0);                  \
  } while (0)

__global__ __launch_bounds__(512, 2) void kan_main(const float* __restrict__ x,
                                                   const u16* __restrict__ wst3,
                                                   float* __restrict__ out) {
  __shared__ __align__(16) char lds[98304];  // 2 x 49152

  const int t = threadIdx.x;
  const int lane = t & 63;
  const int w = t >> 6;
  const int b0 = blockIdx.x * 64;

  if (w < 4) {
    // ================= PRODUCERS =================
    const int pid = (w << 6) + lane;  // 0..255
    const int r0 = pid >> 3;          // 0..31
    const int o = pid & 7;            // k-octet within BK=64 body
    const u32 aw0 = ((u32)(o >> 1) << 10) + ((u32)(o & 1) << 9) +
                    ((u32)((r0 ^ o) & 31) << 4);
    const u32 aw1 = aw0 + 4096;  // g=1 (rows 32..63)
    const float* xpA = x + (size_t)(b0 + r0) * 1024 + o * 8;
    const float* xpB = xpA + 32 * 1024;

    auto rbf6 = [&](char* buf, u32 aw, float4 xa, float4 xb) {
      float xf[8] = {xa.x, xa.y, xa.z, xa.w, xb.x, xb.y, xb.z, xb.w};
      u32 pk[6][4];
#pragma unroll
      for (int pp = 0; pp < 4; ++pp) {
        u32 lo6[6], hi6[6];
#pragma unroll
        for (int e = 0; e < 2; ++e) {
          float xv = xf[2 * pp + e];
          float t0 = C2 * xv;
          float P = __builtin_amdgcn_exp2f(t0 * xv);  // e^{-5x^2}
          float Qp = __builtin_amdgcn_exp2f(-t0);     // e^{+5x}
          float Qm = __builtin_amdgcn_exp2f(t0);      // e^{-5x}
          float PQ = P * Qp, PQm = P * Qm;
          u32* dst = e ? hi6 : lo6;
          dst[0] = __float_as_uint(PQm * Qm * T2C) + 0x8000u;
          dst[1] = __float_as_uint(PQm * T1C) + 0x8000u;
          dst[2] = __float_as_uint(P) + 0x8000u;
          dst[3] = __float_as_uint(PQ * T1C) + 0x8000u;
          dst[4] = __float_as_uint(PQ * Qp * T2C) + 0x8000u;
          dst[5] = __float_as_uint(xv) + 0x8000u;
        }
#pragma unroll
        for (int s = 0; s < 6; ++s)
          pk[s][pp] = __builtin_amdgcn_perm(hi6[s], lo6[s], 0x07060302);
      }
#pragma unroll
      for (int s = 0; s < 6; ++s) {
        uint4 v; v.x = pk[s][0]; v.y = pk[s][1]; v.z = pk[s][2]; v.w = pk[s][3];
        *(uint4*)(buf + s * 8192 + aw) = v;
      }
    };

    // prologue: body 0 -> buf0; then load x for body 1
    float4 xA0 = *(const float4*)(xpA);
    float4 xA1 = *(const float4*)(xpA + 4);
    float4 xB0 = *(const float4*)(xpB);
    float4 xB1 = *(const float4*)(xpB + 4);
    rbf6(lds, aw0, xA0, xA1);
    rbf6(lds, aw1, xB0, xB1);
    xA0 = *(const float4*)(xpA + 64);
    xA1 = *(const float4*)(xpA + 68);
    xB0 = *(const float4*)(xpB + 64);
    xB1 = *(const float4*)(xpB + 68);
    PBAR();  // prologue barrier

    for (int i = 0; i < 16; ++i) {
      if (i < 15) {
        char* nxt = lds + ((i + 1) & 1) * 49152;
        rbf6(nxt, aw0, xA0, xA1);
        rbf6(nxt, aw1, xB0, xB1);
        if (i < 14) {
          xA0 = *(const float4*)(xpA + (i + 2) * 64);
          xA1 = *(const float4*)(xpA + (i + 2) * 64 + 4);
          xB0 = *(const float4*)(xpB + (i + 2) * 64);
          xB1 = *(const float4*)(xpB + (i + 2) * 64 + 4);
        }
      }
      PBAR();  // per-body barriers (x prefetch stays in flight)
    }
    __syncthreads();  // final rendezvous (matches consumer epilogue)
  } else {
    // ================= CONSUMERS =================
    const int wn = w - 4;  // n-quad: cols wn*32 .. +32
    const int m = lane & 31, kh = lane >> 5;
    u32 aoff[4];
#pragma unroll
    for (int p = 0; p < 4; ++p)
      aoff[p] = (u32)(p * 1024 + kh * 512 + (((m ^ (p * 2 + kh)) & 31) << 4));
    const char* bb = (const char*)wst3 + wn * 1024 + lane * 16;

    auto ldB = [&](int chunk, uint4* dst) {
      const char* bc = bb + (size_t)chunk * 24576;
#pragma unroll
      for (int s = 0; s < 6; ++s) dst[s] = *(const uint4*)(bc + s * 4096);
    };

    f32x16 acc[4];  // [0,1]=spline g0/g1, [2,3]=base g0/g1
#pragma unroll
    for (int i = 0; i < 4; ++i)
#pragma unroll
      for (int jj = 0; jj < 16; ++jj) acc[i][jj] = 0.f;

    uint4 bvE[6], bvO[6];  // even/odd chunk sextets (ping-pong)
    ldB(0, bvE);           // chunk 0 in flight across prologue barrier

    RBAR();  // prologue barrier

    for (int i = 0; i < 16; ++i) {
      const char* cur = lds + (i & 1) * 49152;
#pragma unroll
      for (int p = 0; p < 4; ++p) {
        const int c = i * 4 + p;         // c&1 == p&1 (static)
        uint4* bcur = (p & 1) ? bvO : bvE;
        uint4* bnxt = (p & 1) ? bvE : bvO;
        int cn = c + 1; if (cn > 63) cn = 63;
        ldB(cn, bnxt);  // issue next sextet (one full phase of cover)
        uint4 a0[6], a1[6];
#pragma unroll
        for (int s = 0; s < 6; ++s) {
          a0[s] = *(const uint4*)(cur + s * 8192 + aoff[p]);
          a1[s] = *(const uint4*)(cur + s * 8192 + 4096 + aoff[p]);
        }
        __builtin_amdgcn_s_setprio(1);
#pragma unroll
        for (int s = 0; s < 5; ++s) {
          acc[0] = mfma16(a0[s], bcur[s], acc[0]);
          acc[1] = mfma16(a1[s], bcur[s], acc[1]);
        }
        acc[2] = mfma16(a0[5], bcur[5], acc[2]);
        acc[3] = mfma16(a1[5], bcur[5], acc[3]);
        __builtin_amdgcn_s_setprio(0);
      }
      RBAR();  // per-body barriers (B loads stay in flight)
    }

    // ---- epilogue (verbatim R11): waves 6,7 -> LDS; merge by waves 4,5?
    // No: R11 scheme = wn pairs merge via kc... R11 used 4 consumer waves
    // full-K, so NO k-merge is needed: each wave owns its 32 cols fully.
    const int col = wn * 32 + (lane & 31);
    __syncthreads();  // final rendezvous (matches producer tail)
#pragma unroll
    for (int g = 0; g < 2; ++g) {
#pragma unroll
      for (int reg = 0; reg < 16; ++reg) {
        int row = g * 32 + (reg & 3) + 8 * (reg >> 2) + 4 * (lane >> 5);
        float z = acc[2 + g][reg];
        float sv = z / (1.0f + __expf(-z));
        out[(size_t)(b0 + row) * 128 + col] = sv + acc[g][reg];
      }
    }
  }
}

extern "C" void kernel_launch(void* const* d_in, const int* in_sizes, int n_in,
                              void* d_out, int out_size, void* d_ws, size_t ws_size,
                              hipStream_t stream) {
  const float* x  = (const float*)d_in[0];   // [16384][1024] f32
  const float* wb = (const float*)d_in[1];   // [1024][128]   f32
  const float* ws = (const float*)d_in[2];   // [1024][128][8] f32
  u16* wst3 = (u16*)d_ws;                    // [64][1536] granules, 1.5 MB
  float* out = (float*)d_out;                // [16384][128]  f32

  kan_prep<<<dim3(64), 256, 0, stream>>>(wb, ws, wst3);
  kan_main<<<dim3(256), 512, 0, stream>>>(x, wst3, out);
}